// Round 4
// baseline (686.781 us; speedup 1.0000x reference)
//
#include <hip/hip_runtime.h>

// Flash attention fwd: SQ=2048, B=2, H=16, D=64, fp32 in/out, bool mask.
// R4: monolithic (no pre-pass, zero d_ws traffic — harness fill floor dominates
// dur_us, so chain-length is the lever). R1 structure + exp2-domain softmax +
// pkrtz packed converts + double-buffered K/V LDS with ONE barrier per tile
// (commit -> barrier -> compute; register-staged prefetch overlaps compute).
// S^T formulation (q on MFMA lane dim -> per-lane softmax, b64 P writes).

using half2v  = __attribute__((ext_vector_type(2))) _Float16;
using half4v  = __attribute__((ext_vector_type(4))) _Float16;
using half8v  = __attribute__((ext_vector_type(8))) _Float16;
using fp16x2  = __attribute__((ext_vector_type(2))) __fp16;
using float4v = __attribute__((ext_vector_type(4))) float;
using uint4v  = __attribute__((ext_vector_type(4))) unsigned int;

constexpr int SQn = 2048;
constexpr int BHn = 32;            // B*H
constexpr int Dn  = 64;
constexpr int KT  = 64;            // k-tile
constexpr int NT  = SQn / KT;      // 32 tiles
constexpr int QTB = 128;           // q rows per block
constexpr int WQ  = 32;            // q rows per wave
constexpr int KSTR = 72;           // K LDS row stride (halves); 144 B rows, 16B-aligned
constexpr int VSTR = 72;           // V^T LDS row stride
constexpr int PSTR = 72;           // P LDS row stride
constexpr float QSCALE = 0.18033688011112042f;   // (1/sqrt(64)) * log2(e)
constexpr float MASKV  = -14426.95f;             // -10000 * log2(e)

__device__ __forceinline__ half2v pkrtz(float a, float b) {
    fp16x2 r = __builtin_amdgcn_cvt_pkrtz(a, b);
    return __builtin_bit_cast(half2v, r);
}

__global__ __launch_bounds__(256, 2)
void fa_fwd_kernel(const float* __restrict__ Qg, const float* __restrict__ Kg,
                   const float* __restrict__ Vg, const unsigned char* __restrict__ Mg,
                   float* __restrict__ Og)
{
    __shared__ _Float16 Kl[2][KT * KSTR];   // 2 x 9216 B, [k][d]
    __shared__ _Float16 Vl[2][Dn * VSTR];   // 2 x 9216 B, [d][k] (transposed)
    __shared__ _Float16 Pl[4][WQ * PSTR];   // per-wave P / mask staging, 18432 B

    const int tid  = threadIdx.x;
    const int wid  = tid >> 6;
    const int lane = tid & 63;
    const int l15  = lane & 15;
    const int quad = lane >> 4;

    const int bid = blockIdx.x;
    const int bh  = bid >> 4;
    const int qw0 = (bid & 15) * QTB + wid * WQ;

    // ---- Q fragments, converted in-kernel, pre-scaled into exp2 domain ----
    // B-frag of S^T = K*Q^T: lane l15 -> q, quad*8+j -> d (contraction)
    half8v qf[2][2];
#pragma unroll
    for (int qq = 0; qq < 2; ++qq) {
        const float* src = Qg + ((size_t)(qw0 + qq * 16 + l15) * BHn + bh) * Dn + quad * 8;
#pragma unroll
        for (int c = 0; c < 2; ++c) {
            float4v f0 = *(const float4v*)(src + 32 * c);
            float4v f1 = *(const float4v*)(src + 32 * c + 4);
            half8v h;
            ((half2v*)&h)[0] = pkrtz(f0[0] * QSCALE, f0[1] * QSCALE);
            ((half2v*)&h)[1] = pkrtz(f0[2] * QSCALE, f0[3] * QSCALE);
            ((half2v*)&h)[2] = pkrtz(f1[0] * QSCALE, f1[1] * QSCALE);
            ((half2v*)&h)[3] = pkrtz(f1[2] * QSCALE, f1[3] * QSCALE);
            qf[qq][c] = h;
        }
    }

    float mrun[2] = { -1e30f, -1e30f };
    float lrun[2] = { 0.f, 0.f };
    float4v otf[4][2];   // O^T frags: row=d=16td+4quad+r, col=q=l15
#pragma unroll
    for (int td = 0; td < 4; ++td)
#pragma unroll
        for (int qq = 0; qq < 2; ++qq)
            otf[td][qq] = float4v{0.f, 0.f, 0.f, 0.f};

    // ---- staging registers (prefetch overlaps compute of previous tile) ----
    float4v kreg[4], vreg[4];
    uint4v  mreg[2];

    const unsigned char* mp0 = Mg + (size_t)bh * SQn * SQn
                             + (size_t)(qw0 + (lane >> 1)) * SQn + (lane & 1) * 32;

    auto prefetch = [&](int kt) {
        const int k0 = kt * KT;
#pragma unroll
        for (int p = 0; p < 4; ++p) {
            const int flat = p * 256 + tid;
            const int krow = flat >> 4;
            const int d4   = (flat & 15) * 4;
            const size_t off = ((size_t)(k0 + krow) * BHn + bh) * Dn + d4;
            kreg[p] = *(const float4v*)(Kg + off);
            vreg[p] = *(const float4v*)(Vg + off);
        }
        const unsigned char* mp = mp0 + k0;
        mreg[0] = __builtin_nontemporal_load((const uint4v*)mp);
        mreg[1] = __builtin_nontemporal_load((const uint4v*)(mp + 16));
    };

    prefetch(0);

    for (int kt = 0; kt < NT; ++kt) {
        const int buf = kt & 1;

        // ---- commit staged tile (kt) to LDS[buf]; race-free: all waves passed
        // barrier(kt-1), hence finished compute(kt-2), the last reader of buf ----
#pragma unroll
        for (int p = 0; p < 4; ++p) {
            const int flat = p * 256 + tid;
            const int krow = flat >> 4;
            const int d4   = (flat & 15) * 4;
            half4v kh;
            ((half2v*)&kh)[0] = pkrtz(kreg[p][0], kreg[p][1]);
            ((half2v*)&kh)[1] = pkrtz(kreg[p][2], kreg[p][3]);
            *(half4v*)&Kl[buf][krow * KSTR + d4] = kh;
#pragma unroll
            for (int i = 0; i < 4; ++i)
                Vl[buf][(d4 + i) * VSTR + krow] = (_Float16)vreg[p][i];
        }

        // ---- mask fast-path check (wave-uniform); stage into wave-private Pl ----
        unsigned int orv = mreg[0][0] | mreg[0][1] | mreg[0][2] | mreg[0][3]
                         | mreg[1][0] | mreg[1][1] | mreg[1][2] | mreg[1][3];
        const bool mflag = (__ballot(orv != 0u) != 0ull);
        if (mflag) {
            char* mr = (char*)&Pl[wid][0];
            *(uint4v*)(mr + (lane >> 1) * 64 + (lane & 1) * 32)      = mreg[0];
            *(uint4v*)(mr + (lane >> 1) * 64 + (lane & 1) * 32 + 16) = mreg[1];
        }

        __syncthreads();   // LDS[buf] visible; single barrier per tile

        if (kt + 1 < NT) prefetch(kt + 1);   // in flight across compute

        // ---- S^T = K * Q^T : row=k_local=16tk+4quad+r, col=q=l15 ----
        const _Float16* Kb = Kl[buf];
        float4v st[4][2];
#pragma unroll
        for (int tk = 0; tk < 4; ++tk) {
            st[tk][0] = float4v{0.f, 0.f, 0.f, 0.f};
            st[tk][1] = float4v{0.f, 0.f, 0.f, 0.f};
#pragma unroll
            for (int c = 0; c < 2; ++c) {
                half8v ka = *(const half8v*)(Kb + (tk * 16 + l15) * KSTR + c * 32 + quad * 8);
                st[tk][0] = __builtin_amdgcn_mfma_f32_16x16x32_f16(ka, qf[0][c], st[tk][0], 0, 0, 0);
                st[tk][1] = __builtin_amdgcn_mfma_f32_16x16x32_f16(ka, qf[1][c], st[tk][1], 0, 0, 0);
            }
        }

        if (mflag) {
            const unsigned char* mr = (const unsigned char*)&Pl[wid][0];
#pragma unroll
            for (int qq = 0; qq < 2; ++qq)
#pragma unroll
                for (int tk = 0; tk < 4; ++tk)
#pragma unroll
                    for (int r = 0; r < 4; ++r)
                        if (mr[(qq * 16 + l15) * 64 + tk * 16 + quad * 4 + r])
                            st[tk][qq][r] = MASKV;
        }

        // ---- online softmax in exp2 domain (q lane-resident: 2 shuffles) ----
#pragma unroll
        for (int qq = 0; qq < 2; ++qq) {
            float mx = -1e30f;
#pragma unroll
            for (int tk = 0; tk < 4; ++tk)
#pragma unroll
                for (int r = 0; r < 4; ++r) mx = fmaxf(mx, st[tk][qq][r]);
            mx = fmaxf(mx, __shfl_xor(mx, 16));
            mx = fmaxf(mx, __shfl_xor(mx, 32));
            const float mnew  = fmaxf(mrun[qq], mx);
            const float alpha = exp2f(mrun[qq] - mnew);
            mrun[qq] = mnew;

            float ls = 0.f;
#pragma unroll
            for (int tk = 0; tk < 4; ++tk) {
                float p0 = exp2f(st[tk][qq][0] - mnew);
                float p1 = exp2f(st[tk][qq][1] - mnew);
                float p2 = exp2f(st[tk][qq][2] - mnew);
                float p3 = exp2f(st[tk][qq][3] - mnew);
                ls += (p0 + p1) + (p2 + p3);
                half4v ph;
                ((half2v*)&ph)[0] = pkrtz(p0, p1);
                ((half2v*)&ph)[1] = pkrtz(p2, p3);
                *(half4v*)&Pl[wid][(qq * 16 + l15) * PSTR + tk * 16 + quad * 4] = ph;
            }
            ls += __shfl_xor(ls, 16);
            ls += __shfl_xor(ls, 32);
            lrun[qq] = lrun[qq] * alpha + ls;

#pragma unroll
            for (int td = 0; td < 4; ++td)
#pragma unroll
                for (int r = 0; r < 4; ++r) otf[td][qq][r] *= alpha;
        }

        // ---- O^T += V^T * P^T ----
        const _Float16* Vb = Vl[buf];
#pragma unroll
        for (int c2 = 0; c2 < 2; ++c2) {
            half8v pb0 = *(const half8v*)&Pl[wid][(l15) * PSTR + c2 * 32 + quad * 8];
            half8v pb1 = *(const half8v*)&Pl[wid][(16 + l15) * PSTR + c2 * 32 + quad * 8];
#pragma unroll
            for (int td = 0; td < 4; ++td) {
                half8v va = *(const half8v*)(Vb + (td * 16 + l15) * VSTR + c2 * 32 + quad * 8);
                otf[td][0] = __builtin_amdgcn_mfma_f32_16x16x32_f16(va, pb0, otf[td][0], 0, 0, 0);
                otf[td][1] = __builtin_amdgcn_mfma_f32_16x16x32_f16(va, pb1, otf[td][1], 0, 0, 0);
            }
        }
    }

    // ---- epilogue: normalize by l, store ctx[q][b][h*64+d] ----
    const int b = bh >> 4, h = bh & 15;
#pragma unroll
    for (int qq = 0; qq < 2; ++qq) {
        const float inv  = 1.0f / lrun[qq];
        const int   qrow = qw0 + qq * 16 + l15;
        float* dst = Og + ((size_t)qrow * 2 + b) * 1024 + h * 64 + quad * 4;
#pragma unroll
        for (int td = 0; td < 4; ++td) {
            float4v o;
#pragma unroll
            for (int r = 0; r < 4; ++r) o[r] = otf[td][qq][r] * inv;
            *(float4v*)(dst + td * 16) = o;
        }
    }
}

extern "C" void kernel_launch(void* const* d_in, const int* in_sizes, int n_in,
                              void* d_out, int out_size, void* d_ws, size_t ws_size,
                              hipStream_t stream) {
    const float* Q = (const float*)d_in[0];
    const float* K = (const float*)d_in[1];
    const float* V = (const float*)d_in[2];
    const unsigned char* M = (const unsigned char*)d_in[3];
    float* O = (float*)d_out;
    // 512 blocks (16 q-tiles x 32 bh), 256 threads, 54 KB static LDS -> 2 blocks/CU
    hipLaunchKernelGGL(fa_fwd_kernel, dim3(16 * BHn), dim3(256), 0, stream, Q, K, V, M, O);
}